// Round 2
// baseline (1097.438 us; speedup 1.0000x reference)
//
#include <hip/hip_runtime.h>

// ---------- types ----------
typedef __attribute__((ext_vector_type(8))) short short8;   // 8 bf16 (4 VGPRs)
typedef __attribute__((ext_vector_type(4))) float f32x4;    // MFMA accumulator

__device__ __forceinline__ unsigned short f2bf(float f) {
  union { float f; unsigned u; } x{f};
  unsigned r = x.u + 0x7FFFu + ((x.u >> 16) & 1u);  // round-to-nearest-even
  return (unsigned short)(r >> 16);
}

// async global->LDS, 16B per lane; LDS dest is wave-uniform base + lane*16
__device__ __forceinline__ void gload_lds16(const void* g, void* l) {
  __builtin_amdgcn_global_load_lds(
      (__attribute__((address_space(1))) void*)((unsigned long long)g),
      (__attribute__((address_space(3))) void*)(unsigned)((unsigned long long)l),
      16, 0, 0);
}

// ---------- K1: trellis decode -> W[4096][4096] fp32 ----------
__global__ void k_dequant(const int* __restrict__ trellis,
                          const float* __restrict__ tlut,
                          float* __restrict__ W) {
  __shared__ unsigned short words[64];       // 2 tiles * 32 words
  const int t = threadIdx.x;
  if (t < 64) words[t] = (unsigned short)(trellis[(size_t)blockIdx.x * 64 + t] & 0xFFFF);
  __syncthreads();
  const int tl = t >> 7;                     // local tile 0/1
  const int s  = t & 127;
  const unsigned short* w = &words[tl * 32];
  unsigned state = 0;
#pragma unroll
  for (int j = 0; j < 4; ++j) {
    const int ss = (s - j) & 127;
    const unsigned nb = ((unsigned)w[ss >> 2] >> (12 - 4 * (ss & 3))) & 0xFu;
    state |= nb << (4 * j);
  }
  const float2 v = *(const float2*)(tlut + (size_t)state * 2);
  const int tile = blockIdx.x * 2 + tl;
  const int o = ((tile >> 8) << 4) + (s >> 3);
  const int i = ((tile & 255) << 4) + ((s & 7) << 1);
  *(float2*)(W + (size_t)o * 4096 + i) = v;
}

// ---------- K2: FWHT over rows (last axis), in place, * 1/64 ----------
__global__ void k_fwht_row(float* __restrict__ W) {
  __shared__ float row[4096];
  const int t = threadIdx.x;
  float* g = W + ((size_t)blockIdx.x << 12);
#pragma unroll
  for (int k = 0; k < 4; ++k) {
    const int e = (t + (k << 8)) << 2;
    *(float4*)(row + e) = *(const float4*)(g + e);
  }
  __syncthreads();
  for (int h = 1; h < 4096; h <<= 1) {
#pragma unroll
    for (int k = 0; k < 8; ++k) {
      const int p  = t + (k << 8);
      const int j1 = ((p & ~(h - 1)) << 1) | (p & (h - 1));
      const int j2 = j1 + h;
      const float a = row[j1], b = row[j2];
      row[j1] = a + b;
      row[j2] = a - b;
    }
    __syncthreads();
  }
#pragma unroll
  for (int k = 0; k < 4; ++k) {
    const int e = (t + (k << 8)) << 2;
    float4 v = *(float4*)(row + e);
    v.x *= 0.015625f; v.y *= 0.015625f; v.z *= 0.015625f; v.w *= 0.015625f;
    *(float4*)(g + e) = v;
  }
}

// 6-stage H64 butterfly over the first index of tile[64][64]
__device__ __forceinline__ void butterfly64(float (*tile)[64], int t) {
  const int c  = t & 63;
  const int pb = t >> 6;
#pragma unroll
  for (int h = 1; h < 64; h <<= 1) {
#pragma unroll
    for (int k = 0; k < 8; ++k) {
      const int p  = pb + (k << 2);
      const int j1 = ((p & ~(h - 1)) << 1) | (p & (h - 1));
      const int j2 = j1 + h;
      const float a = tile[j1][c], b = tile[j2][c];
      tile[j1][c] = a + b;
      tile[j2][c] = a - b;
    }
    __syncthreads();
  }
}

// ---------- K3a: column FWHT, low 6 bits of row index ----------
__global__ void k_fwht_col1(float* __restrict__ W) {
  __shared__ float tile[64][64];
  const int t  = threadIdx.x;
  const int rg = blockIdx.x >> 6;
  const int cg = blockIdx.x & 63;
  const size_t base = ((size_t)rg << 6) * 4096 + ((size_t)cg << 6);
#pragma unroll
  for (int k = 0; k < 4; ++k) {
    const int idx = t + (k << 8);
    const int r = idx >> 4, c4 = idx & 15;
    *(float4*)(&tile[r][c4 << 2]) = *(const float4*)(W + base + (size_t)r * 4096 + (c4 << 2));
  }
  __syncthreads();
  butterfly64(tile, t);
#pragma unroll
  for (int k = 0; k < 4; ++k) {
    const int idx = t + (k << 8);
    const int r = idx >> 4, c4 = idx & 15;
    *(float4*)(W + base + (size_t)r * 4096 + (c4 << 2)) = *(float4*)(&tile[r][c4 << 2]);
  }
}

// ---------- K3b: column FWHT, high 6 bits, *1/64, *SV[o]*SU[i], -> bf16 Mt[N][K] ----------
__global__ void k_fwht_col2(const float* __restrict__ W,
                            const float* __restrict__ SU,
                            const float* __restrict__ SV,
                            unsigned short* __restrict__ Mt) {
  __shared__ float tile[64][64];
  const int t  = threadIdx.x;
  const int b  = blockIdx.x >> 6;   // row residue (low bits)
  const int cg = blockIdx.x & 63;
#pragma unroll
  for (int k = 0; k < 4; ++k) {
    const int idx = t + (k << 8);
    const int a = idx >> 4, c4 = idx & 15;
    const int row = (a << 6) + b;
    *(float4*)(&tile[a][c4 << 2]) =
        *(const float4*)(W + (size_t)row * 4096 + ((size_t)cg << 6) + (c4 << 2));
  }
  __syncthreads();
  butterfly64(tile, t);
#pragma unroll
  for (int k = 0; k < 4; ++k) {
    const int idx = t + (k << 8);
    const int a = idx >> 4, c4 = idx & 15;
    const int row = (a << 6) + b;                 // o (OUT index)
    const int col0 = (cg << 6) + (c4 << 2);       // i (IN index)
    const float sv = SV[row] * 0.015625f;
    const float4 su = *(const float4*)(SU + col0);
    const float4 v = *(float4*)(&tile[a][c4 << 2]);
    ushort4 o;
    o.x = f2bf(v.x * sv * su.x);
    o.y = f2bf(v.y * sv * su.y);
    o.z = f2bf(v.z * sv * su.z);
    o.w = f2bf(v.w * sv * su.w);
    *(ushort4*)(Mt + (size_t)row * 4096 + col0) = o;
  }
}

// ---------- K5: x fp32 -> bf16 ----------
__global__ void k_cvt_x(const float* __restrict__ x, unsigned short* __restrict__ xb) {
  const long long n4 = (long long)16384 * 4096 / 4;
  long long i = (long long)blockIdx.x * blockDim.x + threadIdx.x;
  const long long stride = (long long)gridDim.x * blockDim.x;
  for (; i < n4; i += stride) {
    const float4 v = *(const float4*)(x + i * 4);
    ushort4 o;
    o.x = f2bf(v.x); o.y = f2bf(v.y); o.z = f2bf(v.z); o.w = f2bf(v.w);
    *(ushort4*)(xb + i * 4) = o;
  }
}

// ---------- K6: GEMM C[16384,4096] = A[16384,4096](bf16) * Mt[4096,4096](bf16 [N][K])^T ----------
// m97 structure (128x128 tile, BK=32, 4 waves, gload_lds w16, 2-barrier K-loop)
// + chunk XOR-swizzle (rule #21: pre-swizzled global SOURCE, linear LDS dest,
//   matching XOR on ds_read) to kill the 8-way bank conflict of the 64B-stride rows
// + bijective XCD swizzle (T1): 512 consecutive blocks per XCD -> A-panel L2 reuse.
__global__ void __launch_bounds__(256) k_gemm(const unsigned short* __restrict__ A,
                                              const unsigned short* __restrict__ B,
                                              float* __restrict__ C) {
  __shared__ unsigned short Asm[128 * 32];  // 8 KB
  __shared__ unsigned short Bsm[128 * 32];  // 8 KB
  const int t    = threadIdx.x;
  const int w    = t >> 6, lane = t & 63;
  const int wr   = w >> 1, wc = w & 1;
  const int lr   = lane & 15, lk = lane >> 4;

  // XCD swizzle: 4096 blocks, 8 XCDs, 512 contiguous per XCD
  const int bid  = ((blockIdx.x & 7) << 9) + (blockIdx.x >> 3);
  const int nt   = bid & 31;   // nt fastest: 32 consecutive blocks share the A panel
  const int mt   = bid >> 5;

  // staging: thread t -> LDS chunk (row=t>>2, c'=t&3); global chunk c = c' ^ ((row>>1)&3)
  const int srcc = ((t & 3) ^ ((t >> 3) & 3)) << 3;   // pre-swizzled source column (elements)
  const unsigned short* aptr = A + (((size_t)(mt * 128 + (t >> 2))) << 12) + srcc;
  const unsigned short* bptr = B + (((size_t)(nt * 128 + (t >> 2))) << 12) + srcc;
  unsigned short* AsmW = Asm + w * 512;   // wave-uniform LDS base
  unsigned short* BsmW = Bsm + w * 512;

  // read-side swizzled chunk offset (elements), lane-constant across mi/ni
  const int ck = (lk ^ ((lr >> 1) & 3)) << 3;

  f32x4 acc[4][4];
#pragma unroll
  for (int i = 0; i < 4; ++i)
#pragma unroll
    for (int j = 0; j < 4; ++j) acc[i][j] = (f32x4){0.f, 0.f, 0.f, 0.f};

  for (int kk = 0; kk < 4096; kk += 32) {
    __syncthreads();                       // previous compute done before overwrite
    gload_lds16(aptr,                 AsmW);
    gload_lds16(aptr + (64ull << 12), AsmW + 2048);
    gload_lds16(bptr,                 BsmW);
    gload_lds16(bptr + (64ull << 12), BsmW + 2048);
    aptr += 32;
    bptr += 32;
    __syncthreads();                       // vmcnt(0)+lgkmcnt drained before barrier

    short8 af[4], bf[4];
#pragma unroll
    for (int mi = 0; mi < 4; ++mi)
      af[mi] = *(const short8*)(Asm + (wr * 64 + mi * 16 + lr) * 32 + ck);
#pragma unroll
    for (int ni = 0; ni < 4; ++ni)
      bf[ni] = *(const short8*)(Bsm + (wc * 64 + ni * 16 + lr) * 32 + ck);
#pragma unroll
    for (int mi = 0; mi < 4; ++mi)
#pragma unroll
      for (int ni = 0; ni < 4; ++ni)
        acc[mi][ni] = __builtin_amdgcn_mfma_f32_16x16x32_bf16(af[mi], bf[ni], acc[mi][ni], 0, 0, 0);
  }

  // C/D layout: col = lane&15, row = (lane>>4)*4 + reg
  float* cbase = C + (((size_t)(mt * 128 + wr * 64 + lk * 4)) << 12) + nt * 128 + wc * 64 + lr;
#pragma unroll
  for (int mi = 0; mi < 4; ++mi)
#pragma unroll
    for (int ni = 0; ni < 4; ++ni)
#pragma unroll
      for (int r = 0; r < 4; ++r)
        cbase[(((size_t)(mi * 16 + r)) << 12) + ni * 16] = acc[mi][ni][r];
}

extern "C" void kernel_launch(void* const* d_in, const int* in_sizes, int n_in,
                              void* d_out, int out_size, void* d_ws, size_t ws_size,
                              hipStream_t stream) {
  const float* x       = (const float*)d_in[0];   // (8,2048,4096) fp32
  const int*   trellis = (const int*)d_in[1];     // (65536,32) int32
  const float* tlut    = (const float*)d_in[2];   // (65536,2) fp32
  const float* SU      = (const float*)d_in[3];   // (4096,)
  const float* SV      = (const float*)d_in[4];   // (4096,)
  float* out = (float*)d_out;

  char* ws = (char*)d_ws;
  float*          W  = (float*)ws;                            // 64 MiB fp32
  unsigned short* Mt = (unsigned short*)(ws + (64ull << 20)); // 32 MiB bf16 [N][K]
  unsigned short* xb = (unsigned short*)(ws + (96ull << 20)); // 128 MiB bf16 [M][K]

  hipLaunchKernelGGL(k_dequant,   dim3(32768), dim3(256), 0, stream, trellis, tlut, W);
  hipLaunchKernelGGL(k_fwht_row,  dim3(4096),  dim3(256), 0, stream, W);
  hipLaunchKernelGGL(k_fwht_col1, dim3(4096),  dim3(256), 0, stream, W);
  hipLaunchKernelGGL(k_fwht_col2, dim3(4096),  dim3(256), 0, stream, W, SU, SV, Mt);
  hipLaunchKernelGGL(k_cvt_x,     dim3(2048),  dim3(256), 0, stream, x, xb);
  hipLaunchKernelGGL(k_gemm,      dim3(4096),  dim3(256), 0, stream, xb, Mt, out);
}

// Round 3
// 642.829 us; speedup vs baseline: 1.7072x; 1.7072x over previous
//
#include <hip/hip_runtime.h>

// ---------- types ----------
typedef __attribute__((ext_vector_type(8))) short short8;   // 8 bf16 (4 VGPRs)
typedef __attribute__((ext_vector_type(4))) float f32x4;    // MFMA accumulator

__device__ __forceinline__ unsigned short f2bf(float f) {
  union { float f; unsigned u; } x{f};
  unsigned r = x.u + 0x7FFFu + ((x.u >> 16) & 1u);  // round-to-nearest-even
  return (unsigned short)(r >> 16);
}

// async global->LDS, 16B per lane; LDS dest is wave-uniform base + lane*16
__device__ __forceinline__ void gload_lds16(const void* g, void* l) {
  __builtin_amdgcn_global_load_lds(
      (__attribute__((address_space(1))) void*)((unsigned long long)g),
      (__attribute__((address_space(3))) void*)(unsigned)((unsigned long long)l),
      16, 0, 0);
}

// ---------- K1: trellis decode -> W[4096][4096] fp32 ----------
__global__ void k_dequant(const int* __restrict__ trellis,
                          const float* __restrict__ tlut,
                          float* __restrict__ W) {
  __shared__ unsigned short words[64];       // 2 tiles * 32 words
  const int t = threadIdx.x;
  if (t < 64) words[t] = (unsigned short)(trellis[(size_t)blockIdx.x * 64 + t] & 0xFFFF);
  __syncthreads();
  const int tl = t >> 7;                     // local tile 0/1
  const int s  = t & 127;
  const unsigned short* w = &words[tl * 32];
  unsigned state = 0;
#pragma unroll
  for (int j = 0; j < 4; ++j) {
    const int ss = (s - j) & 127;
    const unsigned nb = ((unsigned)w[ss >> 2] >> (12 - 4 * (ss & 3))) & 0xFu;
    state |= nb << (4 * j);
  }
  const float2 v = *(const float2*)(tlut + (size_t)state * 2);
  const int tile = blockIdx.x * 2 + tl;
  const int o = ((tile >> 8) << 4) + (s >> 3);
  const int i = ((tile & 255) << 4) + ((s & 7) << 1);
  *(float2*)(W + (size_t)o * 4096 + i) = v;
}

// ---------- K2: FWHT over rows (last axis), in place, * 1/64 ----------
__global__ void k_fwht_row(float* __restrict__ W) {
  __shared__ float row[4096];
  const int t = threadIdx.x;
  float* g = W + ((size_t)blockIdx.x << 12);
#pragma unroll
  for (int k = 0; k < 4; ++k) {
    const int e = (t + (k << 8)) << 2;
    *(float4*)(row + e) = *(const float4*)(g + e);
  }
  __syncthreads();
  for (int h = 1; h < 4096; h <<= 1) {
#pragma unroll
    for (int k = 0; k < 8; ++k) {
      const int p  = t + (k << 8);
      const int j1 = ((p & ~(h - 1)) << 1) | (p & (h - 1));
      const int j2 = j1 + h;
      const float a = row[j1], b = row[j2];
      row[j1] = a + b;
      row[j2] = a - b;
    }
    __syncthreads();
  }
#pragma unroll
  for (int k = 0; k < 4; ++k) {
    const int e = (t + (k << 8)) << 2;
    float4 v = *(float4*)(row + e);
    v.x *= 0.015625f; v.y *= 0.015625f; v.z *= 0.015625f; v.w *= 0.015625f;
    *(float4*)(g + e) = v;
  }
}

// 6-stage H64 butterfly over the first index of tile[64][64]
__device__ __forceinline__ void butterfly64(float (*tile)[64], int t) {
  const int c  = t & 63;
  const int pb = t >> 6;
#pragma unroll
  for (int h = 1; h < 64; h <<= 1) {
#pragma unroll
    for (int k = 0; k < 8; ++k) {
      const int p  = pb + (k << 2);
      const int j1 = ((p & ~(h - 1)) << 1) | (p & (h - 1));
      const int j2 = j1 + h;
      const float a = tile[j1][c], b = tile[j2][c];
      tile[j1][c] = a + b;
      tile[j2][c] = a - b;
    }
    __syncthreads();
  }
}

// ---------- K3a: column FWHT, low 6 bits of row index ----------
__global__ void k_fwht_col1(float* __restrict__ W) {
  __shared__ float tile[64][64];
  const int t  = threadIdx.x;
  const int rg = blockIdx.x >> 6;
  const int cg = blockIdx.x & 63;
  const size_t base = ((size_t)rg << 6) * 4096 + ((size_t)cg << 6);
#pragma unroll
  for (int k = 0; k < 4; ++k) {
    const int idx = t + (k << 8);
    const int r = idx >> 4, c4 = idx & 15;
    *(float4*)(&tile[r][c4 << 2]) = *(const float4*)(W + base + (size_t)r * 4096 + (c4 << 2));
  }
  __syncthreads();
  butterfly64(tile, t);
#pragma unroll
  for (int k = 0; k < 4; ++k) {
    const int idx = t + (k << 8);
    const int r = idx >> 4, c4 = idx & 15;
    *(float4*)(W + base + (size_t)r * 4096 + (c4 << 2)) = *(float4*)(&tile[r][c4 << 2]);
  }
}

// ---------- K3b: column FWHT, high 6 bits, *1/64, *SV[o]*SU[i], -> bf16 Mt[N][K] ----------
__global__ void k_fwht_col2(const float* __restrict__ W,
                            const float* __restrict__ SU,
                            const float* __restrict__ SV,
                            unsigned short* __restrict__ Mt) {
  __shared__ float tile[64][64];
  const int t  = threadIdx.x;
  const int b  = blockIdx.x >> 6;   // row residue (low bits)
  const int cg = blockIdx.x & 63;
#pragma unroll
  for (int k = 0; k < 4; ++k) {
    const int idx = t + (k << 8);
    const int a = idx >> 4, c4 = idx & 15;
    const int row = (a << 6) + b;
    *(float4*)(&tile[a][c4 << 2]) =
        *(const float4*)(W + (size_t)row * 4096 + ((size_t)cg << 6) + (c4 << 2));
  }
  __syncthreads();
  butterfly64(tile, t);
#pragma unroll
  for (int k = 0; k < 4; ++k) {
    const int idx = t + (k << 8);
    const int a = idx >> 4, c4 = idx & 15;
    const int row = (a << 6) + b;                 // o (OUT index)
    const int col0 = (cg << 6) + (c4 << 2);       // i (IN index)
    const float sv = SV[row] * 0.015625f;
    const float4 su = *(const float4*)(SU + col0);
    const float4 v = *(float4*)(&tile[a][c4 << 2]);
    ushort4 o;
    o.x = f2bf(v.x * sv * su.x);
    o.y = f2bf(v.y * sv * su.y);
    o.z = f2bf(v.z * sv * su.z);
    o.w = f2bf(v.w * sv * su.w);
    *(ushort4*)(Mt + (size_t)row * 4096 + col0) = o;
  }
}

// ---------- K5: x fp32 -> bf16 ----------
__global__ void k_cvt_x(const float* __restrict__ x, unsigned short* __restrict__ xb) {
  const long long n4 = (long long)16384 * 4096 / 4;
  long long i = (long long)blockIdx.x * blockDim.x + threadIdx.x;
  const long long stride = (long long)gridDim.x * blockDim.x;
  for (; i < n4; i += stride) {
    const float4 v = *(const float4*)(x + i * 4);
    ushort4 o;
    o.x = f2bf(v.x); o.y = f2bf(v.y); o.z = f2bf(v.z); o.w = f2bf(v.w);
    *(ushort4*)(xb + i * 4) = o;
  }
}

// ---------- K6: 256x256 8-phase GEMM  C[16384,4096] = A * Mt^T ----------
// T3+T4: 8 phases / 2 K-tiles, counted vmcnt(4) at phases 4&8 only (2 half-tiles in flight).
// T2: XOR swizzle chunk^=(row&7), applied pre-swizzled on global source (linear LDS
//     dest for global_load_lds) + same XOR on ds_read -> conflict-free b128 reads.
// T5: setprio(1) around each 16-MFMA cluster.
// LDS 128KiB: A[2dbuf][2half][128][64] bf16 @0, B same @64KiB.
#define BARRIER __builtin_amdgcn_s_barrier()
#define SB0     __builtin_amdgcn_sched_barrier(0)
#define WAITV4  asm volatile("s_waitcnt vmcnt(4)" ::: "memory")
#define WAITV0  asm volatile("s_waitcnt vmcnt(0)" ::: "memory")
#define WAITL0  asm volatile("s_waitcnt lgkmcnt(0)" ::: "memory")

#define STAGE_A(db, h, jj) do { \
  gload_lds16(aRow + (((size_t)((h)*128      )) << 12) + ((jj) << 6), smem +         (db)*32768 + (h)*16384 +        w1k); \
  gload_lds16(aRow + (((size_t)((h)*128 + 64 )) << 12) + ((jj) << 6), smem +         (db)*32768 + (h)*16384 + 8192 + w1k); \
} while (0)
#define STAGE_B(db, h, jj) do { \
  gload_lds16(bRow + (((size_t)((h)*128      )) << 12) + ((jj) << 6), smem + 65536 + (db)*32768 + (h)*16384 +        w1k); \
  gload_lds16(bRow + (((size_t)((h)*128 + 64 )) << 12) + ((jj) << 6), smem + 65536 + (db)*32768 + (h)*16384 + 8192 + w1k); \
} while (0)

#define RD_A(kk, base, cx) do { _Pragma("unroll") \
  for (int mi = 0; mi < 8; ++mi) af[mi][kk] = *(const short8*)((base) + mi*2048 + (cx)); } while (0)
#define RD_B(kk, base, cx) do { _Pragma("unroll") \
  for (int ni = 0; ni < 4; ++ni) bb[ni][kk] = *(const short8*)((base) + ni*2048 + (cx)); } while (0)

#define MMA(nA, nB, kk) do { _Pragma("unroll") \
  for (int mi = 0; mi < 8; ++mi) { \
    acc[mi][nA] = __builtin_amdgcn_mfma_f32_16x16x32_bf16(af[mi][kk], bb[nA][kk], acc[mi][nA], 0, 0, 0); \
    acc[mi][nB] = __builtin_amdgcn_mfma_f32_16x16x32_bf16(af[mi][kk], bb[nB][kk], acc[mi][nB], 0, 0, 0); \
  } } while (0)

#define PHASE(READS, STAGE, WAIT, MMAC) do { \
  READS; STAGE; WAIT; \
  BARRIER; WAITL0; SB0; \
  __builtin_amdgcn_s_setprio(1); MMAC; __builtin_amdgcn_s_setprio(0); \
  BARRIER; SB0; \
} while (0)

__global__ void __launch_bounds__(512, 2)
k_gemm8(const unsigned short* __restrict__ A,
        const unsigned short* __restrict__ B,
        float* __restrict__ C) {
  extern __shared__ char smem[];
  const int t    = threadIdx.x;
  const int lane = t & 63, w = t >> 6;
  const int wr   = w >> 2, wc = w & 3;          // 2 x 4 wave grid
  const int hb   = wc >> 1, rb = (wc & 1) * 64; // B half / row base within half
  const int lr   = lane & 15, q = lane >> 4;
  const int w1k  = w * 1024;

  const int nt = blockIdx.x & 15;               // 16 N-tiles
  const int mt = blockIdx.x >> 4;               // 64 M-tiles

  // frag read offsets (bytes within a [128][64] half): row*128 + (chunk^(row&7))*16
  const int cx0 = lr * 128 + (((0 + q) ^ (lr & 7)) << 4);
  const int cx1 = lr * 128 + (((4 + q) ^ (lr & 7)) << 4);

  // LDS read bases
  const char* As0 = smem +         wr * 16384;            // A dbuf0, half=wr
  const char* As1 = smem + 32768 + wr * 16384;            // A dbuf1
  const char* Bs0 = smem + 65536 +         hb * 16384 + rb * 128;
  const char* Bs1 = smem + 65536 + 32768 + hb * 16384 + rb * 128;

  // staging source: row = (t>>3) within 64-row sub, chunk pre-swizzled c^(row&7)
  const int srow  = t >> 3;
  const int csrc8 = (((t & 7) ^ (srow & 7)) << 3);
  const unsigned short* aRow = A + (((size_t)(mt * 256 + srow)) << 12) + csrc8;
  const unsigned short* bRow = B + (((size_t)(nt * 256 + srow)) << 12) + csrc8;

  short8 af[8][2], bb[4][2];
  f32x4  acc[8][4];
#pragma unroll
  for (int i = 0; i < 8; ++i)
#pragma unroll
    for (int j = 0; j < 4; ++j) acc[i][j] = (f32x4){0.f, 0.f, 0.f, 0.f};

  // prologue: K-tile 0 (4 HTs) + A halves of K-tile 1
  STAGE_A(0, 0, 0); STAGE_A(0, 1, 0); STAGE_B(0, 0, 0); STAGE_B(0, 1, 0);
  STAGE_A(1, 0, 1); STAGE_A(1, 1, 1);
  WAITV4;           // K-tile 0 fully landed; A(1) may remain in flight
  BARRIER; SB0;

  for (int g = 0; g < 31; ++g) {
    const int j1 = 2 * g + 1, j2 = 2 * g + 2, j3 = 2 * g + 3;
    // ---- K-tile 2g from dbuf0 ----
    PHASE({ RD_A(0, As0, cx0); RD_B(0, Bs0, cx0); }, STAGE_B(1, 0, j1), , MMA(0, 1, 0));
    PHASE({ RD_A(1, As0, cx1); },                    STAGE_B(1, 1, j1), , MMA(2, 3, 0));
    PHASE({ RD_B(1, Bs0, cx1); },                    STAGE_A(0, 0, j2), , MMA(0, 1, 1));
    PHASE({ },                                       STAGE_A(0, 1, j2), WAITV4, MMA(2, 3, 1));
    // ---- K-tile 2g+1 from dbuf1 ----
    PHASE({ RD_A(0, As1, cx0); RD_B(0, Bs1, cx0); }, STAGE_B(0, 0, j2), , MMA(0, 1, 0));
    PHASE({ RD_A(1, As1, cx1); },                    STAGE_B(0, 1, j2), , MMA(2, 3, 0));
    PHASE({ RD_B(1, Bs1, cx1); },                    STAGE_A(1, 0, j3), , MMA(0, 1, 1));
    PHASE({ },                                       STAGE_A(1, 1, j3), WAITV4, MMA(2, 3, 1));
  }
  // ---- tail group g=31: K-tiles 62,63; only B(63) left to stage ----
  PHASE({ RD_A(0, As0, cx0); RD_B(0, Bs0, cx0); }, STAGE_B(1, 0, 63), , MMA(0, 1, 0));
  PHASE({ RD_A(1, As0, cx1); },                    STAGE_B(1, 1, 63), , MMA(2, 3, 0));
  PHASE({ RD_B(1, Bs0, cx1); },                    ,                   , MMA(0, 1, 1));
  PHASE({ },                                       ,                   WAITV0, MMA(2, 3, 1));
  PHASE({ RD_A(0, As1, cx0); RD_B(0, Bs1, cx0); }, ,                   , MMA(0, 1, 0));
  PHASE({ RD_A(1, As1, cx1); },                    ,                   , MMA(2, 3, 0));
  PHASE({ RD_B(1, Bs1, cx1); },                    ,                   , MMA(0, 1, 1));
  PHASE({ },                                       ,                   , MMA(2, 3, 1));

  // epilogue: C/D layout col=lane&15, row=(lane>>4)*4+reg
  float* cbase = C + (((size_t)(mt * 256 + wr * 128 + q * 4)) << 12)
               + nt * 256 + wc * 64 + lr;
#pragma unroll
  for (int mi = 0; mi < 8; ++mi)
#pragma unroll
    for (int ni = 0; ni < 4; ++ni)
#pragma unroll
      for (int r = 0; r < 4; ++r)
        cbase[(((size_t)(mi * 16 + r)) << 12) + ni * 16] = acc[mi][ni][r];
}

extern "C" void kernel_launch(void* const* d_in, const int* in_sizes, int n_in,
                              void* d_out, int out_size, void* d_ws, size_t ws_size,
                              hipStream_t stream) {
  const float* x       = (const float*)d_in[0];   // (8,2048,4096) fp32
  const int*   trellis = (const int*)d_in[1];     // (65536,32) int32
  const float* tlut    = (const float*)d_in[2];   // (65536,2) fp32
  const float* SU      = (const float*)d_in[3];   // (4096,)
  const float* SV      = (const float*)d_in[4];   // (4096,)
  float* out = (float*)d_out;

  char* ws = (char*)d_ws;
  float*          W  = (float*)ws;                            // 64 MiB fp32
  unsigned short* Mt = (unsigned short*)(ws + (64ull << 20)); // 32 MiB bf16 [N][K]
  unsigned short* xb = (unsigned short*)(ws + (96ull << 20)); // 128 MiB bf16 [M][K]

  hipFuncSetAttribute(reinterpret_cast<const void*>(&k_gemm8),
                      hipFuncAttributeMaxDynamicSharedMemorySize, 131072);

  hipLaunchKernelGGL(k_dequant,   dim3(32768), dim3(256), 0, stream, trellis, tlut, W);
  hipLaunchKernelGGL(k_fwht_row,  dim3(4096),  dim3(256), 0, stream, W);
  hipLaunchKernelGGL(k_fwht_col1, dim3(4096),  dim3(256), 0, stream, W);
  hipLaunchKernelGGL(k_fwht_col2, dim3(4096),  dim3(256), 0, stream, W, SU, SV, Mt);
  hipLaunchKernelGGL(k_cvt_x,     dim3(2048),  dim3(256), 0, stream, x, xb);
  hipLaunchKernelGGL(k_gemm8,     dim3(1024),  dim3(512), 131072, stream, xb, Mt, out);
}

// Round 4
// 614.138 us; speedup vs baseline: 1.7870x; 1.0467x over previous
//
#include <hip/hip_runtime.h>

// ---------- types ----------
typedef __attribute__((ext_vector_type(8))) short short8;   // 8 bf16 (4 VGPRs)
typedef __attribute__((ext_vector_type(4))) float f32x4;    // MFMA accumulator

__device__ __forceinline__ unsigned short f2bf(float f) {
  union { float f; unsigned u; } x{f};
  unsigned r = x.u + 0x7FFFu + ((x.u >> 16) & 1u);  // round-to-nearest-even
  return (unsigned short)(r >> 16);
}

// async global->LDS, 16B per lane; LDS dest is wave-uniform base + lane*16
__device__ __forceinline__ void gload_lds16(const void* g, void* l) {
  __builtin_amdgcn_global_load_lds(
      (__attribute__((address_space(1))) void*)((unsigned long long)g),
      (__attribute__((address_space(3))) void*)(unsigned)((unsigned long long)l),
      16, 0, 0);
}

// 6-stage H64 butterfly over the first index of tile[64][64]
__device__ __forceinline__ void butterfly64(float (*tile)[64], int t) {
  const int c  = t & 63;
  const int pb = t >> 6;
#pragma unroll
  for (int h = 1; h < 64; h <<= 1) {
#pragma unroll
    for (int k = 0; k < 8; ++k) {
      const int p  = pb + (k << 2);
      const int j1 = ((p & ~(h - 1)) << 1) | (p & (h - 1));
      const int j2 = j1 + h;
      const float a = tile[j1][c], b = tile[j2][c];
      tile[j1][c] = a + b;
      tile[j2][c] = a - b;
    }
    __syncthreads();
  }
}

// ---------- K1: fused trellis decode + col-FWHT(low 6 bits of o) -> W[4096][4096] ----------
// A 64x64 W-region = 16 trellis tiles, fully block-local. o-low butterfly commutes
// with the i-axis FWHT done later. Saves one full 128MB r+w pass vs separate col1.
__global__ void k_deq_col1(const int* __restrict__ trellis,
                           const float* __restrict__ tlut,
                           float* __restrict__ W) {
  __shared__ unsigned short words[16][32];   // 16 tiles * 32 words
  __shared__ float tile[64][64];
  const int t  = threadIdx.x;
  const int rg = blockIdx.x >> 6;            // o-group (64 rows)
  const int cg = blockIdx.x & 63;            // i-group (64 cols)
  // load 512 trellis words (tiles (rg*4+a)*256 + cg*4+b, a,b in 0..3)
#pragma unroll
  for (int r = 0; r < 2; ++r) {
    const int ff = t + (r << 8);
    const int a = ff >> 7, rw = ff & 127;    // rw = b*32 + w (contiguous per a)
    const int src = ((rg * 4 + a) * 256 + cg * 4) * 32 + rw;
    ((unsigned short*)words)[a * 128 + rw] = (unsigned short)(trellis[src] & 0xFFFF);
  }
  __syncthreads();
  // decode 16 tiles x 128 states, 8 per thread
#pragma unroll
  for (int r = 0; r < 8; ++r) {
    const int f  = t + (r << 8);
    const int tl = f >> 7, s = f & 127;
    const unsigned short* w = words[tl];
    unsigned state = 0;
#pragma unroll
    for (int j = 0; j < 4; ++j) {
      const int ss = (s - j) & 127;
      state |= (((unsigned)w[ss >> 2] >> (12 - 4 * (ss & 3))) & 0xFu) << (4 * j);
    }
    const float2 v = *(const float2*)(tlut + (size_t)state * 2);
    const int o = ((tl >> 2) << 4) + (s >> 3);
    const int i = ((tl & 3) << 4) + ((s & 7) << 1);
    tile[o][i]     = v.x;
    tile[o][i + 1] = v.y;
  }
  __syncthreads();
  butterfly64(tile, t);
  const size_t base = ((size_t)(rg * 64)) * 4096 + cg * 64;
#pragma unroll
  for (int k = 0; k < 4; ++k) {
    const int idx = t + (k << 8);
    const int r = idx >> 4, c4 = idx & 15;
    *(float4*)(W + base + (size_t)r * 4096 + (c4 << 2)) = *(float4*)(&tile[r][c4 << 2]);
  }
}

// ---------- K2: FWHT over rows (i axis, full H4096), in place, * 1/64 ----------
__global__ void k_fwht_row(float* __restrict__ W) {
  __shared__ float row[4096];
  const int t = threadIdx.x;
  float* g = W + ((size_t)blockIdx.x << 12);
#pragma unroll
  for (int k = 0; k < 4; ++k) {
    const int e = (t + (k << 8)) << 2;
    *(float4*)(row + e) = *(const float4*)(g + e);
  }
  __syncthreads();
  for (int h = 1; h < 4096; h <<= 1) {
#pragma unroll
    for (int k = 0; k < 8; ++k) {
      const int p  = t + (k << 8);
      const int j1 = ((p & ~(h - 1)) << 1) | (p & (h - 1));
      const int j2 = j1 + h;
      const float a = row[j1], b = row[j2];
      row[j1] = a + b;
      row[j2] = a - b;
    }
    __syncthreads();
  }
#pragma unroll
  for (int k = 0; k < 4; ++k) {
    const int e = (t + (k << 8)) << 2;
    float4 v = *(float4*)(row + e);
    v.x *= 0.015625f; v.y *= 0.015625f; v.z *= 0.015625f; v.w *= 0.015625f;
    *(float4*)(g + e) = v;
  }
}

// ---------- K3: col FWHT, high 6 bits of o, *1/64, *SV[o]*SU[i], -> bf16 Mt[N][K] ----------
__global__ void k_fwht_col2(const float* __restrict__ W,
                            const float* __restrict__ SU,
                            const float* __restrict__ SV,
                            unsigned short* __restrict__ Mt) {
  __shared__ float tile[64][64];
  const int t  = threadIdx.x;
  const int b  = blockIdx.x >> 6;   // row residue (low bits)
  const int cg = blockIdx.x & 63;
#pragma unroll
  for (int k = 0; k < 4; ++k) {
    const int idx = t + (k << 8);
    const int a = idx >> 4, c4 = idx & 15;
    const int row = (a << 6) + b;
    *(float4*)(&tile[a][c4 << 2]) =
        *(const float4*)(W + (size_t)row * 4096 + ((size_t)cg << 6) + (c4 << 2));
  }
  __syncthreads();
  butterfly64(tile, t);
#pragma unroll
  for (int k = 0; k < 4; ++k) {
    const int idx = t + (k << 8);
    const int a = idx >> 4, c4 = idx & 15;
    const int row = (a << 6) + b;                 // o (OUT index)
    const int col0 = (cg << 6) + (c4 << 2);       // i (IN index)
    const float sv = SV[row] * 0.015625f;
    const float4 su = *(const float4*)(SU + col0);
    const float4 v = *(float4*)(&tile[a][c4 << 2]);
    ushort4 o;
    o.x = f2bf(v.x * sv * su.x);
    o.y = f2bf(v.y * sv * su.y);
    o.z = f2bf(v.z * sv * su.z);
    o.w = f2bf(v.w * sv * su.w);
    *(ushort4*)(Mt + (size_t)row * 4096 + col0) = o;
  }
}

// ---------- K4: x fp32 -> bf16 ----------
__global__ void k_cvt_x(const float* __restrict__ x, unsigned short* __restrict__ xb) {
  const long long n4 = (long long)16384 * 4096 / 4;
  long long i = (long long)blockIdx.x * blockDim.x + threadIdx.x;
  const long long stride = (long long)gridDim.x * blockDim.x;
  for (; i < n4; i += stride) {
    const float4 v = *(const float4*)(x + i * 4);
    ushort4 o;
    o.x = f2bf(v.x); o.y = f2bf(v.y); o.z = f2bf(v.z); o.w = f2bf(v.w);
    *(ushort4*)(xb + i * 4) = o;
  }
}

// ---------- K5: 256x256 8-phase GEMM  C[16384,4096] = A * Mt^T ----------
// T3+T4: counted vmcnt(4) at phases 4&8; lgkm now COUNTED too — no explicit
// lgkmcnt(0): compiler emits per-dependency waits, so phase p's MFMA waits only
// its actual operands (p2: 2 reads, p3: 2, p4: 0) instead of draining the queue.
// T2: XOR swizzle chunk^=(row&7) pre-swizzled on global source + same XOR on read.
// T5: setprio(1) around each 16-MFMA cluster.
#define BARRIER __builtin_amdgcn_s_barrier()
#define WAITV4  asm volatile("s_waitcnt vmcnt(4)" ::: "memory")
#define WAITV0  asm volatile("s_waitcnt vmcnt(0)" ::: "memory")

#define STAGE_A(db, h, jj) do { \
  gload_lds16(aRow + (((size_t)((h)*128      )) << 12) + ((jj) << 6), smem +         (db)*32768 + (h)*16384 +        w1k); \
  gload_lds16(aRow + (((size_t)((h)*128 + 64 )) << 12) + ((jj) << 6), smem +         (db)*32768 + (h)*16384 + 8192 + w1k); \
} while (0)
#define STAGE_B(db, h, jj) do { \
  gload_lds16(bRow + (((size_t)((h)*128      )) << 12) + ((jj) << 6), smem + 65536 + (db)*32768 + (h)*16384 +        w1k); \
  gload_lds16(bRow + (((size_t)((h)*128 + 64 )) << 12) + ((jj) << 6), smem + 65536 + (db)*32768 + (h)*16384 + 8192 + w1k); \
} while (0)

#define RD_A(kk, base, cx) do { _Pragma("unroll") \
  for (int mi = 0; mi < 8; ++mi) af[mi][kk] = *(const short8*)((base) + mi*2048 + (cx)); } while (0)
#define RD_B(kk, base, cx) do { _Pragma("unroll") \
  for (int ni = 0; ni < 4; ++ni) bb[ni][kk] = *(const short8*)((base) + ni*2048 + (cx)); } while (0)

#define MMA(nA, nB, kk) do { _Pragma("unroll") \
  for (int mi = 0; mi < 8; ++mi) { \
    acc[mi][nA] = __builtin_amdgcn_mfma_f32_16x16x32_bf16(af[mi][kk], bb[nA][kk], acc[mi][nA], 0, 0, 0); \
    acc[mi][nB] = __builtin_amdgcn_mfma_f32_16x16x32_bf16(af[mi][kk], bb[nB][kk], acc[mi][nB], 0, 0, 0); \
  } } while (0)

#define PHASE(READS, STAGE, WAIT, MMAC) do { \
  READS; STAGE; WAIT; \
  BARRIER; \
  __builtin_amdgcn_s_setprio(1); MMAC; __builtin_amdgcn_s_setprio(0); \
  BARRIER; \
} while (0)

__global__ void __launch_bounds__(512, 2)
k_gemm8(const unsigned short* __restrict__ A,
        const unsigned short* __restrict__ B,
        float* __restrict__ C) {
  extern __shared__ char smem[];
  const int t    = threadIdx.x;
  const int lane = t & 63, w = t >> 6;
  const int wr   = w >> 2, wc = w & 3;          // 2 x 4 wave grid
  const int hb   = wc >> 1, rb = (wc & 1) * 64; // B half / row base within half
  const int lr   = lane & 15, q = lane >> 4;
  const int w1k  = w * 1024;

  const int nt = blockIdx.x & 15;               // 16 N-tiles
  const int mt = blockIdx.x >> 4;               // 64 M-tiles

  // frag read offsets (bytes within a [128][64] half): row*128 + (chunk^(row&7))*16
  const int cx0 = lr * 128 + (((0 + q) ^ (lr & 7)) << 4);
  const int cx1 = lr * 128 + (((4 + q) ^ (lr & 7)) << 4);

  // LDS read bases
  const char* As0 = smem +         wr * 16384;            // A dbuf0, half=wr
  const char* As1 = smem + 32768 + wr * 16384;            // A dbuf1
  const char* Bs0 = smem + 65536 +         hb * 16384 + rb * 128;
  const char* Bs1 = smem + 65536 + 32768 + hb * 16384 + rb * 128;

  // staging source: row = (t>>3) within 64-row sub, chunk pre-swizzled c^(row&7)
  const int srow  = t >> 3;
  const int csrc8 = (((t & 7) ^ (srow & 7)) << 3);
  const unsigned short* aRow = A + (((size_t)(mt * 256 + srow)) << 12) + csrc8;
  const unsigned short* bRow = B + (((size_t)(nt * 256 + srow)) << 12) + csrc8;

  short8 af[8][2], bb[4][2];
  f32x4  acc[8][4];
#pragma unroll
  for (int i = 0; i < 8; ++i)
#pragma unroll
    for (int j = 0; j < 4; ++j) acc[i][j] = (f32x4){0.f, 0.f, 0.f, 0.f};

  // prologue: K-tile 0 (4 HTs) + A halves of K-tile 1
  STAGE_A(0, 0, 0); STAGE_A(0, 1, 0); STAGE_B(0, 0, 0); STAGE_B(0, 1, 0);
  STAGE_A(1, 0, 1); STAGE_A(1, 1, 1);
  WAITV4;           // K-tile 0 fully landed; A(1) may remain in flight
  BARRIER;

  for (int g = 0; g < 31; ++g) {
    const int j1 = 2 * g + 1, j2 = 2 * g + 2, j3 = 2 * g + 3;
    // ---- K-tile 2g from dbuf0 ----
    PHASE({ RD_B(0, Bs0, cx0); RD_A(0, As0, cx0); }, STAGE_B(1, 0, j1), , MMA(0, 1, 0));
    PHASE({ RD_A(1, As0, cx1); },                    STAGE_B(1, 1, j1), , MMA(2, 3, 0));
    PHASE({ RD_B(1, Bs0, cx1); },                    STAGE_A(0, 0, j2), , MMA(0, 1, 1));
    PHASE({ },                                       STAGE_A(0, 1, j2), WAITV4, MMA(2, 3, 1));
    // ---- K-tile 2g+1 from dbuf1 ----
    PHASE({ RD_B(0, Bs1, cx0); RD_A(0, As1, cx0); }, STAGE_B(0, 0, j2), , MMA(0, 1, 0));
    PHASE({ RD_A(1, As1, cx1); },                    STAGE_B(0, 1, j2), , MMA(2, 3, 0));
    PHASE({ RD_B(1, Bs1, cx1); },                    STAGE_A(1, 0, j3), , MMA(0, 1, 1));
    PHASE({ },                                       STAGE_A(1, 1, j3), WAITV4, MMA(2, 3, 1));
  }
  // ---- tail group g=31: K-tiles 62,63; only B(63) left to stage ----
  PHASE({ RD_B(0, Bs0, cx0); RD_A(0, As0, cx0); }, STAGE_B(1, 0, 63), , MMA(0, 1, 0));
  PHASE({ RD_A(1, As0, cx1); },                    STAGE_B(1, 1, 63), , MMA(2, 3, 0));
  PHASE({ RD_B(1, Bs0, cx1); },                    ,                   , MMA(0, 1, 1));
  PHASE({ },                                       ,                   WAITV0, MMA(2, 3, 1));
  PHASE({ RD_B(0, Bs1, cx0); RD_A(0, As1, cx0); }, ,                   , MMA(0, 1, 0));
  PHASE({ RD_A(1, As1, cx1); },                    ,                   , MMA(2, 3, 0));
  PHASE({ RD_B(1, Bs1, cx1); },                    ,                   , MMA(0, 1, 1));
  PHASE({ },                                       ,                   , MMA(2, 3, 1));

  // epilogue: C/D layout col=lane&15, row=(lane>>4)*4+reg
  float* cbase = C + (((size_t)(mt * 256 + wr * 128 + q * 4)) << 12)
               + nt * 256 + wc * 64 + lr;
#pragma unroll
  for (int mi = 0; mi < 8; ++mi)
#pragma unroll
    for (int ni = 0; ni < 4; ++ni)
#pragma unroll
      for (int r = 0; r < 4; ++r)
        cbase[(((size_t)(mi * 16 + r)) << 12) + ni * 16] = acc[mi][ni][r];
}

extern "C" void kernel_launch(void* const* d_in, const int* in_sizes, int n_in,
                              void* d_out, int out_size, void* d_ws, size_t ws_size,
                              hipStream_t stream) {
  const float* x       = (const float*)d_in[0];   // (8,2048,4096) fp32
  const int*   trellis = (const int*)d_in[1];     // (65536,32) int32
  const float* tlut    = (const float*)d_in[2];   // (65536,2) fp32
  const float* SU      = (const float*)d_in[3];   // (4096,)
  const float* SV      = (const float*)d_in[4];   // (4096,)
  float* out = (float*)d_out;

  char* ws = (char*)d_ws;
  float*          W  = (float*)ws;                            // 64 MiB fp32
  unsigned short* Mt = (unsigned short*)(ws + (64ull << 20)); // 32 MiB bf16 [N][K]
  unsigned short* xb = (unsigned short*)(ws + (96ull << 20)); // 128 MiB bf16 [M][K]

  hipFuncSetAttribute(reinterpret_cast<const void*>(&k_gemm8),
                      hipFuncAttributeMaxDynamicSharedMemorySize, 131072);

  hipLaunchKernelGGL(k_deq_col1,  dim3(4096),  dim3(256), 0, stream, trellis, tlut, W);
  hipLaunchKernelGGL(k_fwht_row,  dim3(4096),  dim3(256), 0, stream, W);
  hipLaunchKernelGGL(k_fwht_col2, dim3(4096),  dim3(256), 0, stream, W, SU, SV, Mt);
  hipLaunchKernelGGL(k_cvt_x,     dim3(2048),  dim3(256), 0, stream, x, xb);
  hipLaunchKernelGGL(k_gemm8,     dim3(1024),  dim3(512), 131072, stream, xb, Mt, out);
}